// Round 1
// baseline (2471.928 us; speedup 1.0000x reference)
//
#include <hip/hip_runtime.h>
#include <hip/hip_bf16.h>

#define TILE_M 64

// round-to-nearest-even float -> bf16 bits
__device__ __forceinline__ unsigned short f2bf(float f) {
    union { float f; unsigned int u; } a; a.f = f;
    unsigned int r = a.u + 0x7FFFu + ((a.u >> 16) & 1u);
    return (unsigned short)(r >> 16);
}

// Fused GEMM: computes k = x@Wk+bk, q = x@Wq+bq, v = x@Wv+bv (stored bf16 in ws)
// and out = x@Wskip + bias (fp32, the skip term the edge kernel accumulates onto).
// blockIdx.x = 64-row tile, blockIdx.y = which matrix (0..3).
__global__ __launch_bounds__(256) void gemm_kqvs(
    const float* __restrict__ x, int N,
    const float* __restrict__ Wk, const float* __restrict__ bk,
    const float* __restrict__ Wq, const float* __restrict__ bq,
    const float* __restrict__ Wv, const float* __restrict__ bv,
    const float* __restrict__ Ws, const float* __restrict__ bs,
    unsigned short* __restrict__ kws, unsigned short* __restrict__ qws,
    unsigned short* __restrict__ vws, float* __restrict__ out)
{
    __shared__ float xs[TILE_M][132];   // pad 128->132: staging stores ~conflict-lite, compute reads broadcast
    const int r0 = blockIdx.x * TILE_M;
    const int t = threadIdx.x;

    // stage 64x128 fp32 x-tile (float4, coalesced)
    #pragma unroll
    for (int i = 0; i < 8; ++i) {
        int fl = t + i * 256;           // 0..2047 float4 slots
        int row = fl >> 5;
        int c4  = (fl & 31) << 2;
        float4 val = make_float4(0.f, 0.f, 0.f, 0.f);
        int gr = r0 + row;
        if (gr < N) val = *(const float4*)(x + (size_t)gr * 128 + c4);
        *(float4*)&xs[row][c4] = val;
    }
    __syncthreads();

    const int mat = blockIdx.y;
    const float* W; const float* b;
    if (mat == 0)      { W = Wk; b = bk; }
    else if (mat == 1) { W = Wq; b = bq; }
    else if (mat == 2) { W = Wv; b = bv; }
    else               { W = Ws; b = bs; }

    const int c0 = (t & 31) << 2;   // 4 output cols per thread
    const int rl = (t >> 5) << 3;   // 8 output rows per thread

    float acc[8][4] = {};
    #pragma unroll 4
    for (int kk = 0; kk < 128; ++kk) {
        float4 w = *(const float4*)(W + kk * 128 + c0);   // L1/L2-resident (weights are 256 KB total)
        #pragma unroll
        for (int r = 0; r < 8; ++r) {
            float xv = xs[rl + r][kk];                    // broadcast within wave: conflict-free
            acc[r][0] = fmaf(xv, w.x, acc[r][0]);
            acc[r][1] = fmaf(xv, w.y, acc[r][1]);
            acc[r][2] = fmaf(xv, w.z, acc[r][2]);
            acc[r][3] = fmaf(xv, w.w, acc[r][3]);
        }
    }

    const float b0 = b[c0], b1 = b[c0 + 1], b2 = b[c0 + 2], b3 = b[c0 + 3];
    #pragma unroll
    for (int r = 0; r < 8; ++r) {
        int gr = r0 + rl + r;
        if (gr >= N) continue;
        float o0 = acc[r][0] + b0, o1 = acc[r][1] + b1,
              o2 = acc[r][2] + b2, o3 = acc[r][3] + b3;
        if (mat == 3) {
            *(float4*)(out + (size_t)gr * 128 + c0) = make_float4(o0, o1, o2, o3);
        } else {
            ushort4 pk;
            pk.x = f2bf(o0); pk.y = f2bf(o1); pk.z = f2bf(o2); pk.w = f2bf(o3);
            unsigned short* dst = (mat == 0) ? kws : (mat == 1) ? qws : vws;
            *(ushort4*)(dst + (size_t)gr * 128 + c0) = pk;
        }
    }
}

__device__ __forceinline__ void unpack8(uint4 rawv, float* f) {
    unsigned int w[4] = { rawv.x, rawv.y, rawv.z, rawv.w };
    #pragma unroll
    for (int i = 0; i < 4; ++i) {
        f[2 * i]     = __uint_as_float(w[i] << 16);
        f[2 * i + 1] = __uint_as_float(w[i] & 0xFFFF0000u);
    }
}

// Edge phase: 16 threads per edge, 8 features/thread.
// out[dst] += sigmoid(k[dst] + q[src]) * v[src]
__global__ __launch_bounds__(256) void edge_scatter(
    const int* __restrict__ ei, int E,
    const unsigned short* __restrict__ kws,
    const unsigned short* __restrict__ qws,
    const unsigned short* __restrict__ vws,
    float* __restrict__ out)
{
    int t = blockIdx.x * 256 + threadIdx.x;
    int e = t >> 4;
    if (e >= E) return;
    int fg = (t & 15) << 3;
    int s = ei[e];        // src
    int d = ei[E + e];    // dst
    float kf[8], qf[8], vf[8];
    unpack8(*(const uint4*)(kws + (size_t)d * 128 + fg), kf);
    unpack8(*(const uint4*)(qws + (size_t)s * 128 + fg), qf);
    unpack8(*(const uint4*)(vws + (size_t)s * 128 + fg), vf);
    float* orow = out + (size_t)d * 128 + fg;
    #pragma unroll
    for (int j = 0; j < 8; ++j) {
        float z = kf[j] + qf[j];
        float eta = 1.0f / (1.0f + __expf(-z));
        unsafeAtomicAdd(orow + j, eta * vf[j]);   // hw global_atomic_add_f32
    }
}

extern "C" void kernel_launch(void* const* d_in, const int* in_sizes, int n_in,
                              void* d_out, int out_size, void* d_ws, size_t ws_size,
                              hipStream_t stream) {
    const float* x    = (const float*)d_in[0];
    const int*   ei   = (const int*)d_in[1];
    // d_in[2] = edge_attr (unused by reference math)
    const float* Wk   = (const float*)d_in[3];
    const float* bk   = (const float*)d_in[4];
    const float* Wq   = (const float*)d_in[5];
    const float* bq   = (const float*)d_in[6];
    const float* Wv   = (const float*)d_in[7];
    const float* bv   = (const float*)d_in[8];
    const float* Ws   = (const float*)d_in[9];
    const float* bias = (const float*)d_in[10];

    int N = in_sizes[0] / 128;
    int E = in_sizes[1] / 2;
    float* out = (float*)d_out;

    unsigned short* kws = (unsigned short*)d_ws;
    unsigned short* qws = kws + (size_t)N * 128;
    unsigned short* vws = qws + (size_t)N * 128;

    dim3 g1((N + TILE_M - 1) / TILE_M, 4);
    gemm_kqvs<<<g1, 256, 0, stream>>>(x, N, Wk, bk, Wq, bq, Wv, bv, Ws, bias,
                                      kws, qws, vws, out);

    long long tthreads = (long long)E * 16;
    int tblocks = (int)((tthreads + 255) / 256);
    edge_scatter<<<tblocks, 256, 0, stream>>>(ei, E, kws, qws, vws, out);
}

// Round 2
// 441.622 us; speedup vs baseline: 5.5974x; 5.5974x over previous
//
#include <hip/hip_runtime.h>
#include <hip/hip_bf16.h>

#define TILE_M 64

// round-to-nearest-even float -> bf16 bits
__device__ __forceinline__ unsigned short f2bf(float f) {
    union { float f; unsigned int u; } a; a.f = f;
    unsigned int r = a.u + 0x7FFFu + ((a.u >> 16) & 1u);
    return (unsigned short)(r >> 16);
}

// ---------------- Phase 1: fused GEMMs ----------------
// k = x@Wk+bk, q = x@Wq+bq, v = x@Wv+bv  (bf16 into ws)
// out = x@Wskip + bias                   (fp32; gather adds onto it)
__global__ __launch_bounds__(256) void gemm_kqvs(
    const float* __restrict__ x, int N,
    const float* __restrict__ Wk, const float* __restrict__ bk,
    const float* __restrict__ Wq, const float* __restrict__ bq,
    const float* __restrict__ Wv, const float* __restrict__ bv,
    const float* __restrict__ Ws, const float* __restrict__ bs,
    unsigned short* __restrict__ kws, unsigned short* __restrict__ qws,
    unsigned short* __restrict__ vws, float* __restrict__ out)
{
    __shared__ float xs[TILE_M][132];
    const int r0 = blockIdx.x * TILE_M;
    const int t = threadIdx.x;

    #pragma unroll
    for (int i = 0; i < 8; ++i) {
        int fl = t + i * 256;
        int row = fl >> 5;
        int c4  = (fl & 31) << 2;
        float4 val = make_float4(0.f, 0.f, 0.f, 0.f);
        int gr = r0 + row;
        if (gr < N) val = *(const float4*)(x + (size_t)gr * 128 + c4);
        *(float4*)&xs[row][c4] = val;
    }
    __syncthreads();

    const int mat = blockIdx.y;
    const float* W; const float* b;
    if (mat == 0)      { W = Wk; b = bk; }
    else if (mat == 1) { W = Wq; b = bq; }
    else if (mat == 2) { W = Wv; b = bv; }
    else               { W = Ws; b = bs; }

    const int c0 = (t & 31) << 2;
    const int rl = (t >> 5) << 3;

    float acc[8][4] = {};
    #pragma unroll 4
    for (int kk = 0; kk < 128; ++kk) {
        float4 w = *(const float4*)(W + kk * 128 + c0);
        #pragma unroll
        for (int r = 0; r < 8; ++r) {
            float xv = xs[rl + r][kk];
            acc[r][0] = fmaf(xv, w.x, acc[r][0]);
            acc[r][1] = fmaf(xv, w.y, acc[r][1]);
            acc[r][2] = fmaf(xv, w.z, acc[r][2]);
            acc[r][3] = fmaf(xv, w.w, acc[r][3]);
        }
    }

    const float b0 = b[c0], b1 = b[c0 + 1], b2 = b[c0 + 2], b3 = b[c0 + 3];
    #pragma unroll
    for (int r = 0; r < 8; ++r) {
        int gr = r0 + rl + r;
        if (gr >= N) continue;
        float o0 = acc[r][0] + b0, o1 = acc[r][1] + b1,
              o2 = acc[r][2] + b2, o3 = acc[r][3] + b3;
        if (mat == 3) {
            *(float4*)(out + (size_t)gr * 128 + c0) = make_float4(o0, o1, o2, o3);
        } else {
            ushort4 pk;
            pk.x = f2bf(o0); pk.y = f2bf(o1); pk.z = f2bf(o2); pk.w = f2bf(o3);
            unsigned short* dst = (mat == 0) ? kws : (mat == 1) ? qws : vws;
            *(ushort4*)(dst + (size_t)gr * 128 + c0) = pk;
        }
    }
}

// ---------------- Phase 2: device-built CSR (counting sort by dst) ----------------

__global__ __launch_bounds__(256) void zero_ints(int* __restrict__ p, int n) {
    int i = blockIdx.x * 256 + threadIdx.x;
    if (i < n) p[i] = 0;
}

__global__ __launch_bounds__(256) void count_deg(
    const int* __restrict__ ei, int E, int* __restrict__ deg)
{
    int e = blockIdx.x * 256 + threadIdx.x;
    if (e >= E) return;
    atomicAdd(&deg[ei[E + e]], 1);   // dst
}

// chunk = 1024 elements per block; block-local exclusive scan -> rowStart (no global offset yet)
__global__ __launch_bounds__(256) void scan_chunks(
    const int* __restrict__ deg, int N, int* __restrict__ rowStart,
    int* __restrict__ chunkTot)
{
    __shared__ int sums[256];
    const int t = threadIdx.x;
    const int base = blockIdx.x * 1024 + t * 4;
    int d0 = 0, d1 = 0, d2 = 0, d3 = 0;
    if (base + 3 < N) {
        int4 dd = *(const int4*)(deg + base);
        d0 = dd.x; d1 = dd.y; d2 = dd.z; d3 = dd.w;
    } else {
        if (base + 0 < N) d0 = deg[base + 0];
        if (base + 1 < N) d1 = deg[base + 1];
        if (base + 2 < N) d2 = deg[base + 2];
        if (base + 3 < N) d3 = deg[base + 3];
    }
    int tot = d0 + d1 + d2 + d3;
    sums[t] = tot;
    __syncthreads();
    // Hillis-Steele inclusive scan over 256 thread sums
    #pragma unroll
    for (int off = 1; off < 256; off <<= 1) {
        int v = (t >= off) ? sums[t - off] : 0;
        __syncthreads();
        sums[t] += v;
        __syncthreads();
    }
    int excl = sums[t] - tot;   // exclusive prefix for this thread's 4 elems
    if (base + 0 < N) rowStart[base + 0] = excl;
    if (base + 1 < N) rowStart[base + 1] = excl + d0;
    if (base + 2 < N) rowStart[base + 2] = excl + d0 + d1;
    if (base + 3 < N) rowStart[base + 3] = excl + d0 + d1 + d2;
    if (t == 255) chunkTot[blockIdx.x] = sums[255];
}

__global__ void scan_tops(const int* __restrict__ chunkTot,
                          int* __restrict__ chunkOff, int nChunks)
{
    if (threadIdx.x == 0 && blockIdx.x == 0) {
        int run = 0;
        for (int b = 0; b < nChunks; ++b) { chunkOff[b] = run; run += chunkTot[b]; }
    }
}

__global__ __launch_bounds__(256) void add_offsets(
    int* __restrict__ rowStart, int* __restrict__ rowEnd,
    const int* __restrict__ chunkOff, int N)
{
    int i = blockIdx.x * 256 + threadIdx.x;
    if (i >= N) return;
    int v = rowStart[i] + chunkOff[i >> 10];
    rowStart[i] = v;
    rowEnd[i] = v;    // fill_csr bumps this; after fill it equals segment end
}

__global__ __launch_bounds__(256) void fill_csr(
    const int* __restrict__ ei, int E,
    int* __restrict__ rowEnd, int* __restrict__ elist)
{
    int e = blockIdx.x * 256 + threadIdx.x;
    if (e >= E) return;
    int s = ei[e];
    int d = ei[E + e];
    int pos = atomicAdd(&rowEnd[d], 1);
    elist[pos] = s;
}

// ---------------- Phase 3: owner-computes aggregation (no atomics) ----------------
// One wave per dst node; lane owns 2 features (bf16x2 dword loads, coalesced).
__global__ __launch_bounds__(256) void gather_agg(
    const int* __restrict__ rowStart, const int* __restrict__ rowEnd,
    const int* __restrict__ elist,
    const unsigned short* __restrict__ kws,
    const unsigned short* __restrict__ qws,
    const unsigned short* __restrict__ vws,
    float* __restrict__ out, int N)
{
    int wid = (blockIdx.x * 256 + threadIdx.x) >> 6;   // dst node
    if (wid >= N) return;
    int fo = (threadIdx.x & 63) * 2;                   // 2 feats per lane

    unsigned int kraw = *(const unsigned int*)(kws + (size_t)wid * 128 + fo);
    float k0 = __uint_as_float(kraw << 16);
    float k1 = __uint_as_float(kraw & 0xFFFF0000u);
    float a0 = 0.f, a1 = 0.f;

    int p = rowStart[wid], e = rowEnd[wid];
    for (; p < e; ++p) {
        int s = elist[p];   // same for all lanes -> broadcast
        unsigned int qraw = *(const unsigned int*)(qws + (size_t)s * 128 + fo);
        unsigned int vraw = *(const unsigned int*)(vws + (size_t)s * 128 + fo);
        float q0 = __uint_as_float(qraw << 16);
        float q1 = __uint_as_float(qraw & 0xFFFF0000u);
        float v0 = __uint_as_float(vraw << 16);
        float v1 = __uint_as_float(vraw & 0xFFFF0000u);
        float e0 = __fdividef(1.f, 1.f + __expf(-(k0 + q0)));
        float e1 = __fdividef(1.f, 1.f + __expf(-(k1 + q1)));
        a0 = fmaf(e0, v0, a0);
        a1 = fmaf(e1, v1, a1);
    }

    float2 sk = *(float2*)(out + (size_t)wid * 128 + fo);   // skip+bias from gemm
    sk.x += a0; sk.y += a1;
    *(float2*)(out + (size_t)wid * 128 + fo) = sk;
}

extern "C" void kernel_launch(void* const* d_in, const int* in_sizes, int n_in,
                              void* d_out, int out_size, void* d_ws, size_t ws_size,
                              hipStream_t stream) {
    const float* x    = (const float*)d_in[0];
    const int*   ei   = (const int*)d_in[1];
    const float* Wk   = (const float*)d_in[3];
    const float* bk   = (const float*)d_in[4];
    const float* Wq   = (const float*)d_in[5];
    const float* bq   = (const float*)d_in[6];
    const float* Wv   = (const float*)d_in[7];
    const float* bv   = (const float*)d_in[8];
    const float* Ws   = (const float*)d_in[9];
    const float* bias = (const float*)d_in[10];

    const int N = in_sizes[0] / 128;
    const int E = in_sizes[1] / 2;
    float* out = (float*)d_out;

    // workspace layout
    unsigned short* kws = (unsigned short*)d_ws;
    unsigned short* qws = kws + (size_t)N * 128;
    unsigned short* vws = qws + (size_t)N * 128;
    int* deg      = (int*)(vws + (size_t)N * 128);
    int* rowStart = deg + N;
    int* rowEnd   = rowStart + N;
    int* chunkTot = rowEnd + N;
    int* chunkOff = chunkTot + 128;
    int* elist    = chunkOff + 128;

    const int nChunks = (N + 1023) / 1024;

    dim3 g1((N + TILE_M - 1) / TILE_M, 4);
    gemm_kqvs<<<g1, 256, 0, stream>>>(x, N, Wk, bk, Wq, bq, Wv, bv, Ws, bias,
                                      kws, qws, vws, out);

    zero_ints<<<(N + 255) / 256, 256, 0, stream>>>(deg, N);
    count_deg<<<(E + 255) / 256, 256, 0, stream>>>(ei, E, deg);
    scan_chunks<<<nChunks, 256, 0, stream>>>(deg, N, rowStart, chunkTot);
    scan_tops<<<1, 64, 0, stream>>>(chunkTot, chunkOff, nChunks);
    add_offsets<<<(N + 255) / 256, 256, 0, stream>>>(rowStart, rowEnd, chunkOff, N);
    fill_csr<<<(E + 255) / 256, 256, 0, stream>>>(ei, E, rowEnd, elist);

    gather_agg<<<(N * 64 + 255) / 256, 256, 0, stream>>>(
        rowStart, rowEnd, elist, kws, qws, vws, out, N);
}

// Round 3
// 324.688 us; speedup vs baseline: 7.6132x; 1.3601x over previous
//
#include <hip/hip_runtime.h>
#include <hip/hip_bf16.h>

typedef __bf16 v8bf __attribute__((ext_vector_type(8)));
typedef float  v16f __attribute__((ext_vector_type(16)));

// round-to-nearest-even float -> bf16 bits
__device__ __forceinline__ unsigned short f2bf(float f) {
    union { float f; unsigned int u; } a; a.f = f;
    unsigned int r = a.u + 0x7FFFu + ((a.u >> 16) & 1u);
    return (unsigned short)(r >> 16);
}

// ---------------- Phase 0: pack W^T in bf16 ----------------
// Wt[m][n][k] = bf16(W_m[k][n]); 4 mats x 128 x 128
__global__ __launch_bounds__(256) void prep_w(
    const float* __restrict__ Wk, const float* __restrict__ Wq,
    const float* __restrict__ Wv, const float* __restrict__ Ws,
    unsigned short* __restrict__ Wt)
{
    int i = blockIdx.x * 256 + threadIdx.x;      // 0..65535
    int m = i >> 14;
    int r = i & 16383;
    int n = r >> 7, k = r & 127;
    const float* W = (m == 0) ? Wk : (m == 1) ? Wq : (m == 2) ? Wv : Ws;
    Wt[i] = f2bf(W[k * 128 + n]);
}

// ---------------- Phase 1: fused MFMA GEMMs ----------------
// One pass over x. Wave = 32 rows x 128 cols x 4 mats via mfma_f32_32x32x16_bf16.
// k/q/v -> bf16 ws; skip (mat 3) -> fp32 out.
__global__ __launch_bounds__(256) void gemm_kqvs(
    const float* __restrict__ x, int N,
    const unsigned short* __restrict__ Wt,
    const float* __restrict__ bk, const float* __restrict__ bq,
    const float* __restrict__ bv, const float* __restrict__ bs,
    unsigned short* __restrict__ kws, unsigned short* __restrict__ qws,
    unsigned short* __restrict__ vws, float* __restrict__ out)
{
    const int l = threadIdx.x & 63;
    const int w = threadIdx.x >> 6;
    const int r0w = blockIdx.x * 128 + w * 32;      // this wave's 32-row strip
    const int arow = r0w + (l & 31);
    const int kb = (l >> 5) * 8;                    // k-offset within 16-chunk

    // A fragments: a[c] covers k in [c*16, c*16+16); lane holds 8 contiguous k
    v8bf a[8];
    #pragma unroll
    for (int c = 0; c < 8; ++c) {
        if (arow < N) {
            const float* xp = x + (size_t)arow * 128 + c * 16 + kb;
            float4 u0 = *(const float4*)(xp);
            float4 u1 = *(const float4*)(xp + 4);
            a[c][0] = (__bf16)u0.x; a[c][1] = (__bf16)u0.y;
            a[c][2] = (__bf16)u0.z; a[c][3] = (__bf16)u0.w;
            a[c][4] = (__bf16)u1.x; a[c][5] = (__bf16)u1.y;
            a[c][6] = (__bf16)u1.z; a[c][7] = (__bf16)u1.w;
        } else {
            #pragma unroll
            for (int j = 0; j < 8; ++j) a[c][j] = (__bf16)0.f;
        }
    }

    const int colin = l & 31;
    const int rowb  = 4 * (l >> 5);

    #pragma unroll
    for (int m = 0; m < 4; ++m) {
        const unsigned short* wt = Wt + m * 16384;
        const float* bvec = (m == 0) ? bk : (m == 1) ? bq : (m == 2) ? bv : bs;
        #pragma unroll
        for (int ct = 0; ct < 4; ++ct) {
            const int col = ct * 32 + colin;
            const float bcol = bvec[col];
            v16f acc = {};
            #pragma unroll
            for (int c = 0; c < 8; ++c) {
                v8bf b = *(const v8bf*)(wt + col * 128 + c * 16 + kb);
                acc = __builtin_amdgcn_mfma_f32_32x32x16_bf16(a[c], b, acc, 0, 0, 0);
            }
            // C/D: col = lane&31, row = (reg&3) + 8*(reg>>2) + 4*(lane>>5)
            if (m == 3) {
                #pragma unroll
                for (int reg = 0; reg < 16; ++reg) {
                    int row = r0w + rowb + (reg & 3) + 8 * (reg >> 2);
                    if (row < N) out[(size_t)row * 128 + col] = acc[reg] + bcol;
                }
            } else {
                unsigned short* dst = (m == 0) ? kws : (m == 1) ? qws : vws;
                #pragma unroll
                for (int reg = 0; reg < 16; ++reg) {
                    int row = r0w + rowb + (reg & 3) + 8 * (reg >> 2);
                    if (row < N) dst[(size_t)row * 128 + col] = f2bf(acc[reg] + bcol);
                }
            }
        }
    }
}

// ---------------- Phase 2: device-built CSR (counting sort by dst) ----------------

__global__ __launch_bounds__(256) void zero_ints(int* __restrict__ p, int n) {
    int i = blockIdx.x * 256 + threadIdx.x;
    if (i < n) p[i] = 0;
}

__global__ __launch_bounds__(256) void count_deg(
    const int* __restrict__ ei, int E, int* __restrict__ deg)
{
    int e = blockIdx.x * 256 + threadIdx.x;
    if (e >= E) return;
    atomicAdd(&deg[ei[E + e]], 1);   // dst
}

__global__ __launch_bounds__(256) void scan_chunks(
    const int* __restrict__ deg, int N, int* __restrict__ rowStart,
    int* __restrict__ chunkTot)
{
    __shared__ int sums[256];
    const int t = threadIdx.x;
    const int base = blockIdx.x * 1024 + t * 4;
    int d0 = 0, d1 = 0, d2 = 0, d3 = 0;
    if (base + 3 < N) {
        int4 dd = *(const int4*)(deg + base);
        d0 = dd.x; d1 = dd.y; d2 = dd.z; d3 = dd.w;
    } else {
        if (base + 0 < N) d0 = deg[base + 0];
        if (base + 1 < N) d1 = deg[base + 1];
        if (base + 2 < N) d2 = deg[base + 2];
        if (base + 3 < N) d3 = deg[base + 3];
    }
    int tot = d0 + d1 + d2 + d3;
    sums[t] = tot;
    __syncthreads();
    #pragma unroll
    for (int off = 1; off < 256; off <<= 1) {
        int v = (t >= off) ? sums[t - off] : 0;
        __syncthreads();
        sums[t] += v;
        __syncthreads();
    }
    int excl = sums[t] - tot;
    if (base + 0 < N) rowStart[base + 0] = excl;
    if (base + 1 < N) rowStart[base + 1] = excl + d0;
    if (base + 2 < N) rowStart[base + 2] = excl + d0 + d1;
    if (base + 3 < N) rowStart[base + 3] = excl + d0 + d1 + d2;
    if (t == 255) chunkTot[blockIdx.x] = sums[255];
}

// parallel scan over chunk totals (nChunks <= 128), 1 block x 128 threads
__global__ __launch_bounds__(128) void scan_tops(
    const int* __restrict__ chunkTot, int* __restrict__ chunkOff, int nChunks)
{
    __shared__ int s[128];
    int t = threadIdx.x;
    int v = (t < nChunks) ? chunkTot[t] : 0;
    s[t] = v;
    __syncthreads();
    #pragma unroll
    for (int off = 1; off < 128; off <<= 1) {
        int u = (t >= off) ? s[t - off] : 0;
        __syncthreads();
        s[t] += u;
        __syncthreads();
    }
    if (t < nChunks) chunkOff[t] = s[t] - v;   // exclusive
}

__global__ __launch_bounds__(256) void add_offsets(
    int* __restrict__ rowStart, int* __restrict__ rowEnd,
    const int* __restrict__ chunkOff, int N)
{
    int i = blockIdx.x * 256 + threadIdx.x;
    if (i >= N) return;
    int v = rowStart[i] + chunkOff[i >> 10];
    rowStart[i] = v;
    rowEnd[i] = v;
}

__global__ __launch_bounds__(256) void fill_csr(
    const int* __restrict__ ei, int E,
    int* __restrict__ rowEnd, int* __restrict__ elist)
{
    int e = blockIdx.x * 256 + threadIdx.x;
    if (e >= E) return;
    int s = ei[e];
    int d = ei[E + e];
    int pos = atomicAdd(&rowEnd[d], 1);
    elist[pos] = s;
}

// ---------------- Phase 3: owner-computes aggregation (no atomics) ----------------
// 2 nodes per wave (32 lanes each); lane owns 4 feats (8B bf16 loads).
__global__ __launch_bounds__(256) void gather_agg(
    const int* __restrict__ rowStart, const int* __restrict__ rowEnd,
    const int* __restrict__ elist,
    const unsigned short* __restrict__ kws,
    const unsigned short* __restrict__ qws,
    const unsigned short* __restrict__ vws,
    float* __restrict__ out, int N)
{
    int gid = blockIdx.x * 256 + threadIdx.x;
    int node = gid >> 5;
    if (node >= N) return;
    int fo = (gid & 31) << 2;   // 4 feats per lane

    uint2 kraw = *(const uint2*)(kws + (size_t)node * 128 + fo);
    float k0 = __uint_as_float(kraw.x << 16);
    float k1 = __uint_as_float(kraw.x & 0xFFFF0000u);
    float k2 = __uint_as_float(kraw.y << 16);
    float k3 = __uint_as_float(kraw.y & 0xFFFF0000u);
    float a0 = 0.f, a1 = 0.f, a2 = 0.f, a3 = 0.f;

    int p = rowStart[node], e = rowEnd[node];
    for (; p < e; ++p) {
        int s = elist[p];
        uint2 qr = *(const uint2*)(qws + (size_t)s * 128 + fo);
        uint2 vr = *(const uint2*)(vws + (size_t)s * 128 + fo);
        float q0 = __uint_as_float(qr.x << 16);
        float q1 = __uint_as_float(qr.x & 0xFFFF0000u);
        float q2 = __uint_as_float(qr.y << 16);
        float q3 = __uint_as_float(qr.y & 0xFFFF0000u);
        float v0 = __uint_as_float(vr.x << 16);
        float v1 = __uint_as_float(vr.x & 0xFFFF0000u);
        float v2 = __uint_as_float(vr.y << 16);
        float v3 = __uint_as_float(vr.y & 0xFFFF0000u);
        a0 = fmaf(__fdividef(1.f, 1.f + __expf(-(k0 + q0))), v0, a0);
        a1 = fmaf(__fdividef(1.f, 1.f + __expf(-(k1 + q1))), v1, a1);
        a2 = fmaf(__fdividef(1.f, 1.f + __expf(-(k2 + q2))), v2, a2);
        a3 = fmaf(__fdividef(1.f, 1.f + __expf(-(k3 + q3))), v3, a3);
    }

    float4 o = *(float4*)(out + (size_t)node * 128 + fo);   // skip+bias from gemm
    o.x += a0; o.y += a1; o.z += a2; o.w += a3;
    *(float4*)(out + (size_t)node * 128 + fo) = o;
}

extern "C" void kernel_launch(void* const* d_in, const int* in_sizes, int n_in,
                              void* d_out, int out_size, void* d_ws, size_t ws_size,
                              hipStream_t stream) {
    const float* x    = (const float*)d_in[0];
    const int*   ei   = (const int*)d_in[1];
    const float* Wk   = (const float*)d_in[3];
    const float* bk   = (const float*)d_in[4];
    const float* Wq   = (const float*)d_in[5];
    const float* bq   = (const float*)d_in[6];
    const float* Wv   = (const float*)d_in[7];
    const float* bv   = (const float*)d_in[8];
    const float* Ws   = (const float*)d_in[9];
    const float* bias = (const float*)d_in[10];

    const int N = in_sizes[0] / 128;
    const int E = in_sizes[1] / 2;
    float* out = (float*)d_out;

    // workspace layout
    unsigned short* kws = (unsigned short*)d_ws;
    unsigned short* qws = kws + (size_t)N * 128;
    unsigned short* vws = qws + (size_t)N * 128;
    int* deg      = (int*)(vws + (size_t)N * 128);
    int* rowStart = deg + N;
    int* rowEnd   = rowStart + N;
    int* chunkTot = rowEnd + N;
    int* chunkOff = chunkTot + 128;
    int* elist    = chunkOff + 128;
    unsigned short* Wt = (unsigned short*)(elist + E);

    const int nChunks = (N + 1023) / 1024;

    prep_w<<<256, 256, 0, stream>>>(Wk, Wq, Wv, Ws, Wt);
    gemm_kqvs<<<(N + 127) / 128, 256, 0, stream>>>(
        x, N, Wt, bk, bq, bv, bias, kws, qws, vws, out);

    zero_ints<<<(N + 255) / 256, 256, 0, stream>>>(deg, N);
    count_deg<<<(E + 255) / 256, 256, 0, stream>>>(ei, E, deg);
    scan_chunks<<<nChunks, 256, 0, stream>>>(deg, N, rowStart, chunkTot);
    scan_tops<<<1, 128, 0, stream>>>(chunkTot, chunkOff, nChunks);
    add_offsets<<<(N + 255) / 256, 256, 0, stream>>>(rowStart, rowEnd, chunkOff, N);
    fill_csr<<<(E + 255) / 256, 256, 0, stream>>>(ei, E, rowEnd, elist);

    gather_agg<<<(N * 32 + 255) / 256, 256, 0, stream>>>(
        rowStart, rowEnd, elist, kws, qws, vws, out, N);
}

// Round 4
// 317.400 us; speedup vs baseline: 7.7880x; 1.0230x over previous
//
#include <hip/hip_runtime.h>
#include <hip/hip_bf16.h>

typedef __bf16 v4bf __attribute__((ext_vector_type(4)));
typedef __bf16 v8bf __attribute__((ext_vector_type(8)));
typedef float  v16f __attribute__((ext_vector_type(16)));

// round-to-nearest-even float -> bf16 bits
__device__ __forceinline__ unsigned short f2bf(float f) {
    union { float f; unsigned int u; } a; a.f = f;
    unsigned int r = a.u + 0x7FFFu + ((a.u >> 16) & 1u);
    return (unsigned short)(r >> 16);
}

__device__ __forceinline__ void unpack8(uint4 rawv, float* f) {
    unsigned int w[4] = { rawv.x, rawv.y, rawv.z, rawv.w };
    #pragma unroll
    for (int i = 0; i < 4; ++i) {
        f[2 * i]     = __uint_as_float(w[i] << 16);
        f[2 * i + 1] = __uint_as_float(w[i] & 0xFFFF0000u);
    }
}

// ---------------- Phase 0: pack W^T in bf16 ----------------
// Wt[m][n][k] = bf16(W_m[k][n]); 4 mats x 128 x 128
__global__ __launch_bounds__(256) void prep_w(
    const float* __restrict__ Wk, const float* __restrict__ Wq,
    const float* __restrict__ Wv, const float* __restrict__ Ws,
    unsigned short* __restrict__ Wt)
{
    int i = blockIdx.x * 256 + threadIdx.x;      // 0..65535
    int m = i >> 14;
    int r = i & 16383;
    int n = r >> 7, k = r & 127;
    const float* W = (m == 0) ? Wk : (m == 1) ? Wq : (m == 2) ? Wv : Ws;
    Wt[i] = f2bf(W[k * 128 + n]);
}

// ---------------- Phase 1: MFMA GEMM, one matrix per block (blockIdx.y) ----------
// Wave = 32 rows x 128 cols via mfma_f32_32x32x16_bf16. B staged in LDS
// (stride 132 shorts: b64 reads are 2-way bank aliased = free).
__global__ __launch_bounds__(256) void gemm_one(
    const float* __restrict__ x, int N,
    const unsigned short* __restrict__ Wt,
    const float* __restrict__ bk, const float* __restrict__ bq,
    const float* __restrict__ bv, const float* __restrict__ bs,
    unsigned short* __restrict__ kws, unsigned short* __restrict__ qws,
    unsigned short* __restrict__ vws, float* __restrict__ out)
{
    __shared__ unsigned short wlds[128 * 132];   // [col][k], padded
    const int m = blockIdx.y;
    const unsigned short* wsrc = Wt + m * 16384;
    const int t = threadIdx.x;

    // stage this matrix's 32KB W^T into LDS (contiguous 16B global reads)
    #pragma unroll
    for (int i = 0; i < 8; ++i) {
        int g = t + i * 256;                     // 16B chunk id 0..2047
        int col = g >> 4, ch = g & 15;
        uint4 val = ((const uint4*)wsrc)[g];
        unsigned short* d = wlds + col * 132 + ch * 8;
        *(uint2*)d       = make_uint2(val.x, val.y);   // 8B-aligned writes
        *(uint2*)(d + 4) = make_uint2(val.z, val.w);
    }

    const int l = t & 63;
    const int w = t >> 6;
    const int r0w = blockIdx.x * 128 + w * 32;   // wave's 32-row strip
    const int arow = r0w + (l & 31);
    const int kb = (l >> 5) * 8;

    // A fragments: a[c] covers k in [c*16, c*16+16); lane holds 8 contiguous k
    v8bf a[8];
    #pragma unroll
    for (int c = 0; c < 8; ++c) {
        if (arow < N) {
            const float* xp = x + (size_t)arow * 128 + c * 16 + kb;
            float4 u0 = *(const float4*)(xp);
            float4 u1 = *(const float4*)(xp + 4);
            a[c][0] = (__bf16)u0.x; a[c][1] = (__bf16)u0.y;
            a[c][2] = (__bf16)u0.z; a[c][3] = (__bf16)u0.w;
            a[c][4] = (__bf16)u1.x; a[c][5] = (__bf16)u1.y;
            a[c][6] = (__bf16)u1.z; a[c][7] = (__bf16)u1.w;
        } else {
            #pragma unroll
            for (int j = 0; j < 8; ++j) a[c][j] = (__bf16)0.f;
        }
    }

    __syncthreads();

    const float* bvec = (m == 0) ? bk : (m == 1) ? bq : (m == 2) ? bv : bs;
    const int colin = l & 31;
    const int rowb  = 4 * (l >> 5);

    #pragma unroll
    for (int ct = 0; ct < 4; ++ct) {
        const int col = ct * 32 + colin;
        const float bcol = bvec[col];
        const unsigned short* wp = wlds + col * 132 + kb;
        v16f acc = {};
        #pragma unroll
        for (int c = 0; c < 8; ++c) {
            v4bf b0 = *(const v4bf*)(wp + c * 16);
            v4bf b1 = *(const v4bf*)(wp + c * 16 + 4);
            v8bf b = __builtin_shufflevector(b0, b1, 0, 1, 2, 3, 4, 5, 6, 7);
            acc = __builtin_amdgcn_mfma_f32_32x32x16_bf16(a[c], b, acc, 0, 0, 0);
        }
        // C/D: col = lane&31, row = (reg&3) + 8*(reg>>2) + 4*(lane>>5)
        if (m == 3) {
            #pragma unroll
            for (int reg = 0; reg < 16; ++reg) {
                int row = r0w + rowb + (reg & 3) + 8 * (reg >> 2);
                if (row < N) out[(size_t)row * 128 + col] = acc[reg] + bcol;
            }
        } else {
            unsigned short* dst = (m == 0) ? kws : (m == 1) ? qws : vws;
            #pragma unroll
            for (int reg = 0; reg < 16; ++reg) {
                int row = r0w + rowb + (reg & 3) + 8 * (reg >> 2);
                if (row < N) dst[(size_t)row * 128 + col] = f2bf(acc[reg] + bcol);
            }
        }
    }
}

// ---------------- Phase 2: device-built CSR (counting sort by dst) ----------------

__global__ __launch_bounds__(256) void zero_ints(int* __restrict__ p, int n) {
    int i = blockIdx.x * 256 + threadIdx.x;
    if (i < n) p[i] = 0;
}

__global__ __launch_bounds__(256) void count_deg(
    const int* __restrict__ ei, int E, int* __restrict__ deg)
{
    int e = blockIdx.x * 256 + threadIdx.x;
    if (e >= E) return;
    atomicAdd(&deg[ei[E + e]], 1);   // dst
}

__global__ __launch_bounds__(256) void scan_chunks(
    const int* __restrict__ deg, int N, int* __restrict__ rowStart,
    int* __restrict__ chunkTot)
{
    __shared__ int sums[256];
    const int t = threadIdx.x;
    const int base = blockIdx.x * 1024 + t * 4;
    int d0 = 0, d1 = 0, d2 = 0, d3 = 0;
    if (base + 3 < N) {
        int4 dd = *(const int4*)(deg + base);
        d0 = dd.x; d1 = dd.y; d2 = dd.z; d3 = dd.w;
    } else {
        if (base + 0 < N) d0 = deg[base + 0];
        if (base + 1 < N) d1 = deg[base + 1];
        if (base + 2 < N) d2 = deg[base + 2];
        if (base + 3 < N) d3 = deg[base + 3];
    }
    int tot = d0 + d1 + d2 + d3;
    sums[t] = tot;
    __syncthreads();
    #pragma unroll
    for (int off = 1; off < 256; off <<= 1) {
        int v = (t >= off) ? sums[t - off] : 0;
        __syncthreads();
        sums[t] += v;
        __syncthreads();
    }
    int excl = sums[t] - tot;
    if (base + 0 < N) rowStart[base + 0] = excl;
    if (base + 1 < N) rowStart[base + 1] = excl + d0;
    if (base + 2 < N) rowStart[base + 2] = excl + d0 + d1;
    if (base + 3 < N) rowStart[base + 3] = excl + d0 + d1 + d2;
    if (t == 255) chunkTot[blockIdx.x] = sums[255];
}

__global__ __launch_bounds__(128) void scan_tops(
    const int* __restrict__ chunkTot, int* __restrict__ chunkOff, int nChunks)
{
    __shared__ int s[128];
    int t = threadIdx.x;
    int v = (t < nChunks) ? chunkTot[t] : 0;
    s[t] = v;
    __syncthreads();
    #pragma unroll
    for (int off = 1; off < 128; off <<= 1) {
        int u = (t >= off) ? s[t - off] : 0;
        __syncthreads();
        s[t] += u;
        __syncthreads();
    }
    if (t < nChunks) chunkOff[t] = s[t] - v;   // exclusive
}

__global__ __launch_bounds__(256) void add_offsets(
    int* __restrict__ rowStart, int* __restrict__ rowEnd,
    const int* __restrict__ chunkOff, int N)
{
    int i = blockIdx.x * 256 + threadIdx.x;
    if (i >= N) return;
    int v = rowStart[i] + chunkOff[i >> 10];
    rowStart[i] = v;
    rowEnd[i] = v;
}

__global__ __launch_bounds__(256) void fill_csr(
    const int* __restrict__ ei, int E,
    int* __restrict__ rowEnd, int* __restrict__ elist)
{
    int e = blockIdx.x * 256 + threadIdx.x;
    if (e >= E) return;
    int s = ei[e];
    int d = ei[E + e];
    int pos = atomicAdd(&rowEnd[d], 1);
    elist[pos] = s;
}

// ---------------- Phase 3: owner-computes aggregation (no atomics) ----------------
// 4 nodes per wave (16 lanes each); lane owns 8 feats (16B uint4 loads =
// full 256B row per group). Edge loop unrolled x2 for MLP.
__global__ __launch_bounds__(256) void gather_agg(
    const int* __restrict__ rowStart, const int* __restrict__ rowEnd,
    const int* __restrict__ elist,
    const unsigned short* __restrict__ kws,
    const unsigned short* __restrict__ qws,
    const unsigned short* __restrict__ vws,
    float* __restrict__ out, int N)
{
    int gid = blockIdx.x * 256 + threadIdx.x;
    int node = gid >> 4;
    if (node >= N) return;
    int fo = (gid & 15) << 3;   // 8 feats per lane

    float kf[8];
    unpack8(*(const uint4*)(kws + (size_t)node * 128 + fo), kf);
    float acc[8] = {};

    int p = rowStart[node];
    const int e = rowEnd[node];

    for (; p + 2 <= e; p += 2) {
        int s0 = elist[p];
        int s1 = elist[p + 1];
        uint4 q0r = *(const uint4*)(qws + (size_t)s0 * 128 + fo);
        uint4 v0r = *(const uint4*)(vws + (size_t)s0 * 128 + fo);
        uint4 q1r = *(const uint4*)(qws + (size_t)s1 * 128 + fo);
        uint4 v1r = *(const uint4*)(vws + (size_t)s1 * 128 + fo);
        float qf0[8], vf0[8], qf1[8], vf1[8];
        unpack8(q0r, qf0); unpack8(v0r, vf0);
        unpack8(q1r, qf1); unpack8(v1r, vf1);
        #pragma unroll
        for (int j = 0; j < 8; ++j) {
            float e0 = __fdividef(1.f, 1.f + __expf(-(kf[j] + qf0[j])));
            float e1 = __fdividef(1.f, 1.f + __expf(-(kf[j] + qf1[j])));
            acc[j] = fmaf(e0, vf0[j], acc[j]);
            acc[j] = fmaf(e1, vf1[j], acc[j]);
        }
    }
    if (p < e) {
        int s0 = elist[p];
        uint4 q0r = *(const uint4*)(qws + (size_t)s0 * 128 + fo);
        uint4 v0r = *(const uint4*)(vws + (size_t)s0 * 128 + fo);
        float qf0[8], vf0[8];
        unpack8(q0r, qf0); unpack8(v0r, vf0);
        #pragma unroll
        for (int j = 0; j < 8; ++j) {
            float e0 = __fdividef(1.f, 1.f + __expf(-(kf[j] + qf0[j])));
            acc[j] = fmaf(e0, vf0[j], acc[j]);
        }
    }

    float* orow = out + (size_t)node * 128 + fo;
    float4 o0 = *(float4*)(orow);
    float4 o1 = *(float4*)(orow + 4);
    o0.x += acc[0]; o0.y += acc[1]; o0.z += acc[2]; o0.w += acc[3];
    o1.x += acc[4]; o1.y += acc[5]; o1.z += acc[6]; o1.w += acc[7];
    *(float4*)(orow)     = o0;
    *(float4*)(orow + 4) = o1;
}

extern "C" void kernel_launch(void* const* d_in, const int* in_sizes, int n_in,
                              void* d_out, int out_size, void* d_ws, size_t ws_size,
                              hipStream_t stream) {
    const float* x    = (const float*)d_in[0];
    const int*   ei   = (const int*)d_in[1];
    const float* Wk   = (const float*)d_in[3];
    const float* bk   = (const float*)d_in[4];
    const float* Wq   = (const float*)d_in[5];
    const float* bq   = (const float*)d_in[6];
    const float* Wv   = (const float*)d_in[7];
    const float* bv   = (const float*)d_in[8];
    const float* Ws   = (const float*)d_in[9];
    const float* bias = (const float*)d_in[10];

    const int N = in_sizes[0] / 128;
    const int E = in_sizes[1] / 2;
    float* out = (float*)d_out;

    // workspace layout
    unsigned short* kws = (unsigned short*)d_ws;
    unsigned short* qws = kws + (size_t)N * 128;
    unsigned short* vws = qws + (size_t)N * 128;
    int* deg      = (int*)(vws + (size_t)N * 128);
    int* rowStart = deg + N;
    int* rowEnd   = rowStart + N;
    int* chunkTot = rowEnd + N;
    int* chunkOff = chunkTot + 128;
    int* elist    = chunkOff + 128;
    unsigned short* Wt = (unsigned short*)(elist + E);

    const int nChunks = (N + 1023) / 1024;

    prep_w<<<256, 256, 0, stream>>>(Wk, Wq, Wv, Ws, Wt);
    dim3 g1((N + 127) / 128, 4);
    gemm_one<<<g1, 256, 0, stream>>>(
        x, N, Wt, bk, bq, bv, bias, kws, qws, vws, out);

    zero_ints<<<(N + 255) / 256, 256, 0, stream>>>(deg, N);
    count_deg<<<(E + 255) / 256, 256, 0, stream>>>(ei, E, deg);
    scan_chunks<<<nChunks, 256, 0, stream>>>(deg, N, rowStart, chunkTot);
    scan_tops<<<1, 128, 0, stream>>>(chunkTot, chunkOff, nChunks);
    add_offsets<<<(N + 255) / 256, 256, 0, stream>>>(rowStart, rowEnd, chunkOff, N);
    fill_csr<<<(E + 255) / 256, 256, 0, stream>>>(ei, E, rowEnd, elist);

    gather_agg<<<((size_t)N * 16 + 255) / 256, 256, 0, stream>>>(
        rowStart, rowEnd, elist, kws, qws, vws, out, N);
}

// Round 5
// 308.683 us; speedup vs baseline: 8.0080x; 1.0282x over previous
//
#include <hip/hip_runtime.h>
#include <hip/hip_bf16.h>

typedef __bf16 v4bf __attribute__((ext_vector_type(4)));
typedef __bf16 v8bf __attribute__((ext_vector_type(8)));
typedef float  v16f __attribute__((ext_vector_type(16)));

// round-to-nearest-even float -> bf16 bits
__device__ __forceinline__ unsigned short f2bf(float f) {
    union { float f; unsigned int u; } a; a.f = f;
    unsigned int r = a.u + 0x7FFFu + ((a.u >> 16) & 1u);
    return (unsigned short)(r >> 16);
}

__device__ __forceinline__ void unpack8(uint4 rawv, float* f) {
    unsigned int w[4] = { rawv.x, rawv.y, rawv.z, rawv.w };
    #pragma unroll
    for (int i = 0; i < 4; ++i) {
        f[2 * i]     = __uint_as_float(w[i] << 16);
        f[2 * i + 1] = __uint_as_float(w[i] & 0xFFFF0000u);
    }
}

// ---------------- Phase 0: pack W^T bf16 + zero deg (fused) ----------------
__global__ __launch_bounds__(256) void prep_w_zero(
    const float* __restrict__ Wk, const float* __restrict__ Wq,
    const float* __restrict__ Wv, const float* __restrict__ Ws,
    unsigned short* __restrict__ Wt, int* __restrict__ deg, int N)
{
    int i = blockIdx.x * 256 + threadIdx.x;      // 512 blocks -> 131072 threads
    if (i < 65536) {
        int m = i >> 14;
        int r = i & 16383;
        int n = r >> 7, k = r & 127;
        const float* W = (m == 0) ? Wk : (m == 1) ? Wq : (m == 2) ? Wv : Ws;
        Wt[i] = f2bf(W[k * 128 + n]);
    }
    if (i < N) deg[i] = 0;
}

// ---------------- Phase 1: fused MFMA GEMM, x read once ----------------
// 1024 threads = 16 waves = 16 (mat, col-tile) combos. B-frags register-
// resident (loaded once); grid-stride over 32-row x-tiles staged in LDS
// (bf16, stride 132 -> 2-way bank alias = free); next tile prefetched
// into registers before the MFMA chain.
__global__ __launch_bounds__(1024, 4) void gemm_fused(
    const float* __restrict__ x, int N,
    const unsigned short* __restrict__ Wt,
    const float* __restrict__ bk, const float* __restrict__ bq,
    const float* __restrict__ bv, const float* __restrict__ bs,
    unsigned short* __restrict__ kws, unsigned short* __restrict__ qws,
    unsigned short* __restrict__ vws, float* __restrict__ out)
{
    __shared__ __align__(16) unsigned short xs[32 * 132];
    const int t   = threadIdx.x;
    const int wid = t >> 6;          // 0..15
    const int m   = wid >> 2;        // matrix
    const int ct  = wid & 3;         // col tile
    const int l   = t & 63;
    const int col = ct * 32 + (l & 31);
    const int kb  = (l >> 5) * 8;

    // B fragments, loaded once (L2-resident after first blocks)
    v8bf b[8];
    {
        const unsigned short* wp = Wt + m * 16384 + col * 128 + kb;
        #pragma unroll
        for (int c = 0; c < 8; ++c) b[c] = *(const v8bf*)(wp + c * 16);
    }
    const float* bvec = (m == 0) ? bk : (m == 1) ? bq : (m == 2) ? bv : bs;
    const float bcol = bvec[col];
    unsigned short* dst = (m == 0) ? kws : (m == 1) ? qws : vws;

    // staging: thread owns one float4 of the 32x128 tile
    const int srow = t >> 5;         // 0..31
    const int sk4  = (t & 31) << 2;  // 0..124
    const int rowb = 4 * (l >> 5);

    const int ntiles = (N + 31) >> 5;
    int tile = blockIdx.x;
    if (tile >= ntiles) return;

    float4 stg = make_float4(0.f, 0.f, 0.f, 0.f);
    {
        int gr = tile * 32 + srow;
        if (gr < N) stg = *(const float4*)(x + (size_t)gr * 128 + sk4);
    }

    while (true) {
        // write staged tile to LDS as bf16
        ushort4 pk;
        pk.x = f2bf(stg.x); pk.y = f2bf(stg.y);
        pk.z = f2bf(stg.z); pk.w = f2bf(stg.w);
        *(ushort4*)(xs + srow * 132 + sk4) = pk;
        __syncthreads();

        // A fragments from LDS (b64 pairs, 2-way alias = free)
        v8bf a[8];
        {
            const unsigned short* ap = xs + (l & 31) * 132 + kb;
            #pragma unroll
            for (int c = 0; c < 8; ++c) {
                v4bf a0 = *(const v4bf*)(ap + c * 16);
                v4bf a1 = *(const v4bf*)(ap + c * 16 + 4);
                a[c] = __builtin_shufflevector(a0, a1, 0, 1, 2, 3, 4, 5, 6, 7);
            }
        }

        // prefetch next tile while computing this one
        int next = tile + gridDim.x;
        if (next < ntiles) {
            int gr = next * 32 + srow;
            stg = (gr < N) ? *(const float4*)(x + (size_t)gr * 128 + sk4)
                           : make_float4(0.f, 0.f, 0.f, 0.f);
        }

        v16f acc = {};
        #pragma unroll
        for (int c = 0; c < 8; ++c)
            acc = __builtin_amdgcn_mfma_f32_32x32x16_bf16(a[c], b[c], acc, 0, 0, 0);

        // C/D: col = lane&31, row = (reg&3) + 8*(reg>>2) + 4*(lane>>5)
        const int r0 = tile * 32 + rowb;
        if (m == 3) {
            #pragma unroll
            for (int reg = 0; reg < 16; ++reg) {
                int row = r0 + (reg & 3) + 8 * (reg >> 2);
                if (row < N) out[(size_t)row * 128 + col] = acc[reg] + bcol;
            }
        } else {
            #pragma unroll
            for (int reg = 0; reg < 16; ++reg) {
                int row = r0 + (reg & 3) + 8 * (reg >> 2);
                if (row < N) dst[(size_t)row * 128 + col] = f2bf(acc[reg] + bcol);
            }
        }

        tile = next;
        if (tile >= ntiles) break;
        __syncthreads();   // all A-frag reads done before next staging write
    }
}

// ---------------- Phase 2: device-built CSR (counting sort by dst) ----------------

__global__ __launch_bounds__(256) void count_deg(
    const int* __restrict__ ei, int E, int* __restrict__ deg)
{
    int e = blockIdx.x * 256 + threadIdx.x;
    if (e >= E) return;
    atomicAdd(&deg[ei[E + e]], 1);   // dst
}

__global__ __launch_bounds__(256) void scan_chunks(
    const int* __restrict__ deg, int N, int* __restrict__ rowStart,
    int* __restrict__ chunkTot)
{
    __shared__ int sums[256];
    const int t = threadIdx.x;
    const int base = blockIdx.x * 1024 + t * 4;
    int d0 = 0, d1 = 0, d2 = 0, d3 = 0;
    if (base + 3 < N) {
        int4 dd = *(const int4*)(deg + base);
        d0 = dd.x; d1 = dd.y; d2 = dd.z; d3 = dd.w;
    } else {
        if (base + 0 < N) d0 = deg[base + 0];
        if (base + 1 < N) d1 = deg[base + 1];
        if (base + 2 < N) d2 = deg[base + 2];
        if (base + 3 < N) d3 = deg[base + 3];
    }
    int tot = d0 + d1 + d2 + d3;
    sums[t] = tot;
    __syncthreads();
    #pragma unroll
    for (int off = 1; off < 256; off <<= 1) {
        int v = (t >= off) ? sums[t - off] : 0;
        __syncthreads();
        sums[t] += v;
        __syncthreads();
    }
    int excl = sums[t] - tot;
    if (base + 0 < N) rowStart[base + 0] = excl;
    if (base + 1 < N) rowStart[base + 1] = excl + d0;
    if (base + 2 < N) rowStart[base + 2] = excl + d0 + d1;
    if (base + 3 < N) rowStart[base + 3] = excl + d0 + d1 + d2;
    if (t == 255) chunkTot[blockIdx.x] = sums[255];
}

// add chunk offsets; each block re-scans the (<=128) chunk totals in LDS
__global__ __launch_bounds__(256) void add_offsets(
    int* __restrict__ rowStart, int* __restrict__ rowEnd,
    const int* __restrict__ chunkTot, int N, int nChunks)
{
    __shared__ int s[128];
    const int t = threadIdx.x;
    if (t < 128) s[t] = (t < nChunks) ? chunkTot[t] : 0;
    __syncthreads();
    #pragma unroll
    for (int off = 1; off < 128; off <<= 1) {
        int u = 0;
        if (t < 128 && t >= off) u = s[t - off];
        __syncthreads();
        if (t < 128) s[t] += u;
        __syncthreads();
    }
    const int coff = (blockIdx.x == 0) ? 0 : s[blockIdx.x - 1];
    const int base = blockIdx.x * 1024 + t * 4;
    if (base + 3 < N) {
        int4 r = *(const int4*)(rowStart + base);
        r.x += coff; r.y += coff; r.z += coff; r.w += coff;
        *(int4*)(rowStart + base) = r;
        *(int4*)(rowEnd + base) = r;
    } else {
        #pragma unroll
        for (int j = 0; j < 4; ++j) {
            if (base + j < N) {
                int v = rowStart[base + j] + coff;
                rowStart[base + j] = v;
                rowEnd[base + j] = v;
            }
        }
    }
}

__global__ __launch_bounds__(256) void fill_csr(
    const int* __restrict__ ei, int E,
    int* __restrict__ rowEnd, int* __restrict__ elist)
{
    int e = blockIdx.x * 256 + threadIdx.x;
    if (e >= E) return;
    int s = ei[e];
    int d = ei[E + e];
    int pos = atomicAdd(&rowEnd[d], 1);
    elist[pos] = s;
}

// ---------------- Phase 3: owner-computes aggregation (no atomics) ----------------
// 4 nodes/wave (16 lanes each), lane owns 8 feats. Unroll x4: 8 independent
// 16B loads in flight per lane per iteration.
__global__ __launch_bounds__(256) void gather_agg(
    const int* __restrict__ rowStart, const int* __restrict__ rowEnd,
    const int* __restrict__ elist,
    const unsigned short* __restrict__ kws,
    const unsigned short* __restrict__ qws,
    const unsigned short* __restrict__ vws,
    float* __restrict__ out, int N)
{
    int gid = blockIdx.x * 256 + threadIdx.x;
    int node = gid >> 4;
    if (node >= N) return;
    int fo = (gid & 15) << 3;   // 8 feats per lane

    float kf[8];
    unpack8(*(const uint4*)(kws + (size_t)node * 128 + fo), kf);
    float acc[8] = {};

    int p = rowStart[node];
    const int e = rowEnd[node];

    for (; p + 4 <= e; p += 4) {
        int s0 = elist[p], s1 = elist[p + 1], s2 = elist[p + 2], s3 = elist[p + 3];
        uint4 q0r = *(const uint4*)(qws + (size_t)s0 * 128 + fo);
        uint4 v0r = *(const uint4*)(vws + (size_t)s0 * 128 + fo);
        uint4 q1r = *(const uint4*)(qws + (size_t)s1 * 128 + fo);
        uint4 v1r = *(const uint4*)(vws + (size_t)s1 * 128 + fo);
        uint4 q2r = *(const uint4*)(qws + (size_t)s2 * 128 + fo);
        uint4 v2r = *(const uint4*)(vws + (size_t)s2 * 128 + fo);
        uint4 q3r = *(const uint4*)(qws + (size_t)s3 * 128 + fo);
        uint4 v3r = *(const uint4*)(vws + (size_t)s3 * 128 + fo);
        float qf[8], vf[8];
        unpack8(q0r, qf); unpack8(v0r, vf);
        #pragma unroll
        for (int j = 0; j < 8; ++j)
            acc[j] = fmaf(__fdividef(1.f, 1.f + __expf(-(kf[j] + qf[j]))), vf[j], acc[j]);
        unpack8(q1r, qf); unpack8(v1r, vf);
        #pragma unroll
        for (int j = 0; j < 8; ++j)
            acc[j] = fmaf(__fdividef(1.f, 1.f + __expf(-(kf[j] + qf[j]))), vf[j], acc[j]);
        unpack8(q2r, qf); unpack8(v2r, vf);
        #pragma unroll
        for (int j = 0; j < 8; ++j)
            acc[j] = fmaf(__fdividef(1.f, 1.f + __expf(-(kf[j] + qf[j]))), vf[j], acc[j]);
        unpack8(q3r, qf); unpack8(v3r, vf);
        #pragma unroll
        for (int j = 0; j < 8; ++j)
            acc[j] = fmaf(__fdividef(1.f, 1.f + __expf(-(kf[j] + qf[j]))), vf[j], acc[j]);
    }
    for (; p < e; ++p) {
        int s0 = elist[p];
        uint4 q0r = *(const uint4*)(qws + (size_t)s0 * 128 + fo);
        uint4 v0r = *(const uint4*)(vws + (size_t)s0 * 128 + fo);
        float qf[8], vf[8];
        unpack8(q0r, qf); unpack8(v0r, vf);
        #pragma unroll
        for (int j = 0; j < 8; ++j)
            acc[j] = fmaf(__fdividef(1.f, 1.f + __expf(-(kf[j] + qf[j]))), vf[j], acc[j]);
    }

    float* orow = out + (size_t)node * 128 + fo;
    float4 o0 = *(float4*)(orow);
    float4 o1 = *(float4*)(orow + 4);
    o0.x += acc[0]; o0.y += acc[1]; o0.z += acc[2]; o0.w += acc[3];
    o1.x += acc[4]; o1.y += acc[5]; o1.z += acc[6]; o1.w += acc[7];
    *(float4*)(orow)     = o0;
    *(float4*)(orow + 4) = o1;
}

extern "C" void kernel_launch(void* const* d_in, const int* in_sizes, int n_in,
                              void* d_out, int out_size, void* d_ws, size_t ws_size,
                              hipStream_t stream) {
    const float* x    = (const float*)d_in[0];
    const int*   ei   = (const int*)d_in[1];
    const float* Wk   = (const float*)d_in[3];
    const float* bk   = (const float*)d_in[4];
    const float* Wq   = (const float*)d_in[5];
    const float* bq   = (const float*)d_in[6];
    const float* Wv   = (const float*)d_in[7];
    const float* bv   = (const float*)d_in[8];
    const float* Ws   = (const float*)d_in[9];
    const float* bias = (const float*)d_in[10];

    const int N = in_sizes[0] / 128;
    const int E = in_sizes[1] / 2;
    float* out = (float*)d_out;

    // workspace layout
    unsigned short* kws = (unsigned short*)d_ws;
    unsigned short* qws = kws + (size_t)N * 128;
    unsigned short* vws = qws + (size_t)N * 128;
    int* deg      = (int*)(vws + (size_t)N * 128);
    int* rowStart = deg + N;
    int* rowEnd   = rowStart + N;
    int* chunkTot = rowEnd + N;
    int* elist    = chunkTot + 128;
    unsigned short* Wt = (unsigned short*)(elist + E);

    const int nChunks = (N + 1023) / 1024;

    prep_w_zero<<<512, 256, 0, stream>>>(Wk, Wq, Wv, Ws, Wt, deg, N);
    gemm_fused<<<512, 1024, 0, stream>>>(
        x, N, Wt, bk, bq, bv, bias, kws, qws, vws, out);

    count_deg<<<(E + 255) / 256, 256, 0, stream>>>(ei, E, deg);
    scan_chunks<<<nChunks, 256, 0, stream>>>(deg, N, rowStart, chunkTot);
    add_offsets<<<nChunks, 256, 0, stream>>>(rowStart, rowEnd, chunkTot, N, nChunks);
    fill_csr<<<(E + 255) / 256, 256, 0, stream>>>(ei, E, rowEnd, elist);

    gather_agg<<<((size_t)N * 16 + 255) / 256, 256, 0, stream>>>(
        rowStart, rowEnd, elist, kws, qws, vws, out, N);
}

// Round 6
// 302.298 us; speedup vs baseline: 8.1771x; 1.0211x over previous
//
#include <hip/hip_runtime.h>
#include <hip/hip_bf16.h>

typedef __bf16 v4bf __attribute__((ext_vector_type(4)));
typedef __bf16 v8bf __attribute__((ext_vector_type(8)));
typedef float  v16f __attribute__((ext_vector_type(16)));

// round-to-nearest-even float -> bf16 bits
__device__ __forceinline__ unsigned short f2bf(float f) {
    union { float f; unsigned int u; } a; a.f = f;
    unsigned int r = a.u + 0x7FFFu + ((a.u >> 16) & 1u);
    return (unsigned short)(r >> 16);
}

__device__ __forceinline__ void unpack8(uint4 rawv, float* f) {
    unsigned int w[4] = { rawv.x, rawv.y, rawv.z, rawv.w };
    #pragma unroll
    for (int i = 0; i < 4; ++i) {
        f[2 * i]     = __uint_as_float(w[i] << 16);
        f[2 * i + 1] = __uint_as_float(w[i] & 0xFFFF0000u);
    }
}

// ---------------- Phase 0: pack W^T bf16 + zero deg (fused) ----------------
__global__ __launch_bounds__(256) void prep_w_zero(
    const float* __restrict__ Wk, const float* __restrict__ Wq,
    const float* __restrict__ Wv, const float* __restrict__ Ws,
    unsigned short* __restrict__ Wt, int* __restrict__ deg, int N)
{
    int i = blockIdx.x * 256 + threadIdx.x;      // 512 blocks -> 131072 threads
    if (i < 65536) {
        int m = i >> 14;
        int r = i & 16383;
        int n = r >> 7, k = r & 127;
        const float* W = (m == 0) ? Wk : (m == 1) ? Wq : (m == 2) ? Wv : Ws;
        Wt[i] = f2bf(W[k * 128 + n]);
    }
    if (i < N) deg[i] = 0;
}

// ---------------- Phase 1: fused MFMA GEMM, x read once ----------------
// 1024 threads = 16 waves = 16 (mat, col-tile) combos. B-frags register-
// resident; grid-stride over 32-row x-tiles staged in LDS (bf16, stride
// 132 -> 2-way bank alias = free); next tile prefetched into registers.
// A-frag ds_reads fused into the MFMA chain to cut VGPR pressure.
// q and v are written INTERLEAVED: qv[node] = [q 128 | v 128] (bf16).
__global__ __launch_bounds__(1024, 4) void gemm_fused(
    const float* __restrict__ x, int N,
    const unsigned short* __restrict__ Wt,
    const float* __restrict__ bk, const float* __restrict__ bq,
    const float* __restrict__ bv, const float* __restrict__ bs,
    unsigned short* __restrict__ kws, unsigned short* __restrict__ qv,
    float* __restrict__ out)
{
    __shared__ __align__(16) unsigned short xs[32 * 132];
    const int t   = threadIdx.x;
    const int wid = t >> 6;          // 0..15
    const int m   = wid >> 2;        // matrix
    const int ct  = wid & 3;         // col tile
    const int l   = t & 63;
    const int col = ct * 32 + (l & 31);
    const int kb  = (l >> 5) * 8;

    // B fragments, loaded once (L2-resident after first blocks)
    v8bf b[8];
    {
        const unsigned short* wp = Wt + m * 16384 + col * 128 + kb;
        #pragma unroll
        for (int c = 0; c < 8; ++c) b[c] = *(const v8bf*)(wp + c * 16);
    }
    const float* bvec = (m == 0) ? bk : (m == 1) ? bq : (m == 2) ? bv : bs;
    const float bcol = bvec[col];
    unsigned short* dst; int dstride;
    if (m == 0)      { dst = kws;      dstride = 128; }
    else if (m == 1) { dst = qv;       dstride = 256; }
    else             { dst = qv + 128; dstride = 256; }   // m==2 (v half)

    // staging: thread owns one float4 of the 32x128 tile
    const int srow = t >> 5;         // 0..31
    const int sk4  = (t & 31) << 2;  // 0..124
    const int rowb = 4 * (l >> 5);

    const int ntiles = (N + 31) >> 5;
    int tile = blockIdx.x;
    if (tile >= ntiles) return;

    float4 stg = make_float4(0.f, 0.f, 0.f, 0.f);
    {
        int gr = tile * 32 + srow;
        if (gr < N) stg = *(const float4*)(x + (size_t)gr * 128 + sk4);
    }

    const unsigned short* ap = xs + (l & 31) * 132 + kb;

    while (true) {
        // write staged tile to LDS as bf16
        ushort4 pk;
        pk.x = f2bf(stg.x); pk.y = f2bf(stg.y);
        pk.z = f2bf(stg.z); pk.w = f2bf(stg.w);
        *(ushort4*)(xs + srow * 132 + sk4) = pk;
        __syncthreads();

        // prefetch next tile while computing this one
        int next = tile + gridDim.x;
        if (next < ntiles) {
            int gr = next * 32 + srow;
            stg = (gr < N) ? *(const float4*)(x + (size_t)gr * 128 + sk4)
                           : make_float4(0.f, 0.f, 0.f, 0.f);
        }

        // fused LDS-read + MFMA chain (a-frags transient: low VGPR)
        v16f acc = {};
        #pragma unroll
        for (int c = 0; c < 8; ++c) {
            v4bf a0 = *(const v4bf*)(ap + c * 16);
            v4bf a1 = *(const v4bf*)(ap + c * 16 + 4);
            v8bf a = __builtin_shufflevector(a0, a1, 0, 1, 2, 3, 4, 5, 6, 7);
            acc = __builtin_amdgcn_mfma_f32_32x32x16_bf16(a, b[c], acc, 0, 0, 0);
        }

        // C/D: col = lane&31, row = (reg&3) + 8*(reg>>2) + 4*(lane>>5)
        const int r0 = tile * 32 + rowb;
        if (m == 3) {
            #pragma unroll
            for (int reg = 0; reg < 16; ++reg) {
                int row = r0 + (reg & 3) + 8 * (reg >> 2);
                if (row < N) out[(size_t)row * 128 + col] = acc[reg] + bcol;
            }
        } else {
            #pragma unroll
            for (int reg = 0; reg < 16; ++reg) {
                int row = r0 + (reg & 3) + 8 * (reg >> 2);
                if (row < N) dst[(size_t)row * dstride + col] = f2bf(acc[reg] + bcol);
            }
        }

        tile = next;
        if (tile >= ntiles) break;
        __syncthreads();   // all A-frag reads done before next staging write
    }
}

// ---------------- Phase 2: device-built CSR (counting sort by dst) ----------------

__global__ __launch_bounds__(256) void count_deg(
    const int* __restrict__ ei, int E, int* __restrict__ deg)
{
    int e = blockIdx.x * 256 + threadIdx.x;
    if (e >= E) return;
    atomicAdd(&deg[ei[E + e]], 1);   // dst
}

__global__ __launch_bounds__(256) void scan_chunks(
    const int* __restrict__ deg, int N, int* __restrict__ rowStart,
    int* __restrict__ chunkTot)
{
    __shared__ int sums[256];
    const int t = threadIdx.x;
    const int base = blockIdx.x * 1024 + t * 4;
    int d0 = 0, d1 = 0, d2 = 0, d3 = 0;
    if (base + 3 < N) {
        int4 dd = *(const int4*)(deg + base);
        d0 = dd.x; d1 = dd.y; d2 = dd.z; d3 = dd.w;
    } else {
        if (base + 0 < N) d0 = deg[base + 0];
        if (base + 1 < N) d1 = deg[base + 1];
        if (base + 2 < N) d2 = deg[base + 2];
        if (base + 3 < N) d3 = deg[base + 3];
    }
    int tot = d0 + d1 + d2 + d3;
    sums[t] = tot;
    __syncthreads();
    #pragma unroll
    for (int off = 1; off < 256; off <<= 1) {
        int v = (t >= off) ? sums[t - off] : 0;
        __syncthreads();
        sums[t] += v;
        __syncthreads();
    }
    int excl = sums[t] - tot;
    if (base + 0 < N) rowStart[base + 0] = excl;
    if (base + 1 < N) rowStart[base + 1] = excl + d0;
    if (base + 2 < N) rowStart[base + 2] = excl + d0 + d1;
    if (base + 3 < N) rowStart[base + 3] = excl + d0 + d1 + d2;
    if (t == 255) chunkTot[blockIdx.x] = sums[255];
}

// add chunk offsets; each block re-scans the (<=128) chunk totals in LDS
__global__ __launch_bounds__(256) void add_offsets(
    int* __restrict__ rowStart, int* __restrict__ rowEnd,
    const int* __restrict__ chunkTot, int N, int nChunks)
{
    __shared__ int s[128];
    const int t = threadIdx.x;
    if (t < 128) s[t] = (t < nChunks) ? chunkTot[t] : 0;
    __syncthreads();
    #pragma unroll
    for (int off = 1; off < 128; off <<= 1) {
        int u = 0;
        if (t < 128 && t >= off) u = s[t - off];
        __syncthreads();
        if (t < 128) s[t] += u;
        __syncthreads();
    }
    const int coff = (blockIdx.x == 0) ? 0 : s[blockIdx.x - 1];
    const int base = blockIdx.x * 1024 + t * 4;
    if (base + 3 < N) {
        int4 r = *(const int4*)(rowStart + base);
        r.x += coff; r.y += coff; r.z += coff; r.w += coff;
        *(int4*)(rowStart + base) = r;
        *(int4*)(rowEnd + base) = r;
    } else {
        #pragma unroll
        for (int j = 0; j < 4; ++j) {
            if (base + j < N) {
                int v = rowStart[base + j] + coff;
                rowStart[base + j] = v;
                rowEnd[base + j] = v;
            }
        }
    }
}

__global__ __launch_bounds__(256) void fill_csr(
    const int* __restrict__ ei, int E,
    int* __restrict__ rowEnd, int* __restrict__ elist)
{
    int e = blockIdx.x * 256 + threadIdx.x;
    if (e >= E) return;
    int s = ei[e];
    int d = ei[E + e];
    int pos = atomicAdd(&rowEnd[d], 1);
    elist[pos] = s;
}

// ---------------- Phase 3: owner-computes aggregation (no atomics) ----------------
// 4 nodes/wave (16 lanes each), lane owns 8 feats. q|v interleaved per src:
// both 16B loads per edge hit the same 512B row. Unroll x4: 8 independent
// loads in flight per lane.
__global__ __launch_bounds__(256) void gather_agg(
    const int* __restrict__ rowStart, const int* __restrict__ rowEnd,
    const int* __restrict__ elist,
    const unsigned short* __restrict__ kws,
    const unsigned short* __restrict__ qv,
    float* __restrict__ out, int N)
{
    int gid = blockIdx.x * 256 + threadIdx.x;
    int node = gid >> 4;
    if (node >= N) return;
    int fo = (gid & 15) << 3;   // 8 feats per lane

    float kf[8];
    unpack8(*(const uint4*)(kws + (size_t)node * 128 + fo), kf);
    float acc[8] = {};

    const unsigned short* qvb = qv + fo;
    int p = rowStart[node];
    const int e = rowEnd[node];

    for (; p + 4 <= e; p += 4) {
        int s0 = elist[p], s1 = elist[p + 1], s2 = elist[p + 2], s3 = elist[p + 3];
        const unsigned short* r0 = qvb + (size_t)s0 * 256;
        const unsigned short* r1 = qvb + (size_t)s1 * 256;
        const unsigned short* r2 = qvb + (size_t)s2 * 256;
        const unsigned short* r3 = qvb + (size_t)s3 * 256;
        uint4 q0r = *(const uint4*)(r0);
        uint4 v0r = *(const uint4*)(r0 + 128);
        uint4 q1r = *(const uint4*)(r1);
        uint4 v1r = *(const uint4*)(r1 + 128);
        uint4 q2r = *(const uint4*)(r2);
        uint4 v2r = *(const uint4*)(r2 + 128);
        uint4 q3r = *(const uint4*)(r3);
        uint4 v3r = *(const uint4*)(r3 + 128);
        float qf[8], vf[8];
        unpack8(q0r, qf); unpack8(v0r, vf);
        #pragma unroll
        for (int j = 0; j < 8; ++j)
            acc[j] = fmaf(__fdividef(1.f, 1.f + __expf(-(kf[j] + qf[j]))), vf[j], acc[j]);
        unpack8(q1r, qf); unpack8(v1r, vf);
        #pragma unroll
        for (int j = 0; j < 8; ++j)
            acc[j] = fmaf(__fdividef(1.f, 1.f + __expf(-(kf[j] + qf[j]))), vf[j], acc[j]);
        unpack8(q2r, qf); unpack8(v2r, vf);
        #pragma unroll
        for (int j = 0; j < 8; ++j)
            acc[j] = fmaf(__fdividef(1.f, 1.f + __expf(-(kf[j] + qf[j]))), vf[j], acc[j]);
        unpack8(q3r, qf); unpack8(v3r, vf);
        #pragma unroll
        for (int j = 0; j < 8; ++j)
            acc[j] = fmaf(__fdividef(1.f, 1.f + __expf(-(kf[j] + qf[j]))), vf[j], acc[j]);
    }
    for (; p < e; ++p) {
        int s0 = elist[p];
        const unsigned short* r0 = qvb + (size_t)s0 * 256;
        uint4 q0r = *(const uint4*)(r0);
        uint4 v0r = *(const uint4*)(r0 + 128);
        float qf[8], vf[8];
        unpack8(q0r, qf); unpack8(v0r, vf);
        #pragma unroll
        for (int j = 0; j < 8; ++j)
            acc[j] = fmaf(__fdividef(1.f, 1.f + __expf(-(kf[j] + qf[j]))), vf[j], acc[j]);
    }

    float* orow = out + (size_t)node * 128 + fo;
    float4 o0 = *(float4*)(orow);
    float4 o1 = *(float4*)(orow + 4);
    o0.x += acc[0]; o0.y += acc[1]; o0.z += acc[2]; o0.w += acc[3];
    o1.x += acc[4]; o1.y += acc[5]; o1.z += acc[6]; o1.w += acc[7];
    *(float4*)(orow)     = o0;
    *(float4*)(orow + 4) = o1;
}

extern "C" void kernel_launch(void* const* d_in, const int* in_sizes, int n_in,
                              void* d_out, int out_size, void* d_ws, size_t ws_size,
                              hipStream_t stream) {
    const float* x    = (const float*)d_in[0];
    const int*   ei   = (const int*)d_in[1];
    const float* Wk   = (const float*)d_in[3];
    const float* bk   = (const float*)d_in[4];
    const float* Wq   = (const float*)d_in[5];
    const float* bq   = (const float*)d_in[6];
    const float* Wv   = (const float*)d_in[7];
    const float* bv   = (const float*)d_in[8];
    const float* Ws   = (const float*)d_in[9];
    const float* bias = (const float*)d_in[10];

    const int N = in_sizes[0] / 128;
    const int E = in_sizes[1] / 2;
    float* out = (float*)d_out;

    // workspace layout
    unsigned short* kws = (unsigned short*)d_ws;        // N*128 bf16
    unsigned short* qv  = kws + (size_t)N * 128;        // N*256 bf16 (q|v)
    int* deg      = (int*)(qv + (size_t)N * 256);
    int* rowStart = deg + N;
    int* rowEnd   = rowStart + N;
    int* chunkTot = rowEnd + N;
    int* elist    = chunkTot + 128;
    unsigned short* Wt = (unsigned short*)(elist + E);

    const int nChunks = (N + 1023) / 1024;

    prep_w_zero<<<512, 256, 0, stream>>>(Wk, Wq, Wv, Ws, Wt, deg, N);
    gemm_fused<<<512, 1024, 0, stream>>>(
        x, N, Wt, bk, bq, bv, bias, kws, qv, out);

    count_deg<<<(E + 255) / 256, 256, 0, stream>>>(ei, E, deg);
    scan_chunks<<<nChunks, 256, 0, stream>>>(deg, N, rowStart, chunkTot);
    add_offsets<<<nChunks, 256, 0, stream>>>(rowStart, rowEnd, chunkTot, N, nChunks);
    fill_csr<<<(E + 255) / 256, 256, 0, stream>>>(ei, E, rowEnd, elist);

    gather_agg<<<((size_t)N * 16 + 255) / 256, 256, 0, stream>>>(
        rowStart, rowEnd, elist, kws, qv, out, N);
}

// Round 7
// 282.879 us; speedup vs baseline: 8.7385x; 1.0686x over previous
//
#include <hip/hip_runtime.h>
#include <hip/hip_bf16.h>

typedef __bf16 v4bf __attribute__((ext_vector_type(4)));
typedef __bf16 v8bf __attribute__((ext_vector_type(8)));
typedef float  v16f __attribute__((ext_vector_type(16)));

#define LOG2E 1.44269504088896340736f

// round-to-nearest-even float -> bf16 bits
__device__ __forceinline__ unsigned short f2bf(float f) {
    union { float f; unsigned int u; } a; a.f = f;
    unsigned int r = a.u + 0x7FFFu + ((a.u >> 16) & 1u);
    return (unsigned short)(r >> 16);
}

__device__ __forceinline__ void unpack8(uint4 rawv, float* f) {
    unsigned int w[4] = { rawv.x, rawv.y, rawv.z, rawv.w };
    #pragma unroll
    for (int i = 0; i < 4; ++i) {
        f[2 * i]     = __uint_as_float(w[i] << 16);
        f[2 * i + 1] = __uint_as_float(w[i] & 0xFFFF0000u);
    }
}

// ---------------- Phase 0: pack W^T bf16 + zero deg (fused) ----------------
// k & q weights pre-scaled by log2(e): they feed ONLY sigmoid(k+q), so
// sigmoid becomes 1/(1+2^-(k'+q')) -> raw v_exp_f32, no per-edge mul.
__global__ __launch_bounds__(256) void prep_w_zero(
    const float* __restrict__ Wk, const float* __restrict__ Wq,
    const float* __restrict__ Wv, const float* __restrict__ Ws,
    unsigned short* __restrict__ Wt, int* __restrict__ deg, int N)
{
    int i = blockIdx.x * 256 + threadIdx.x;      // 512 blocks -> 131072 threads
    if (i < 65536) {
        int m = i >> 14;
        int r = i & 16383;
        int n = r >> 7, k = r & 127;
        const float* W = (m == 0) ? Wk : (m == 1) ? Wq : (m == 2) ? Wv : Ws;
        float scale = (m < 2) ? LOG2E : 1.0f;
        Wt[i] = f2bf(W[k * 128 + n] * scale);
    }
    if (i < N) deg[i] = 0;
}

// ---------------- Phase 1: fused MFMA GEMM, x read once ----------------
// 1024 threads = 16 waves = 16 (mat, col-tile) combos. B-frags register-
// resident; grid-stride over 32-row x-tiles staged in LDS (bf16, stride
// 132 -> 2-way bank alias = free); next tile prefetched into registers.
// q and v written INTERLEAVED: qv[node] = [q' 128 | v 128] (bf16).
__global__ __launch_bounds__(1024, 4) void gemm_fused(
    const float* __restrict__ x, int N,
    const unsigned short* __restrict__ Wt,
    const float* __restrict__ bk, const float* __restrict__ bq,
    const float* __restrict__ bv, const float* __restrict__ bs,
    unsigned short* __restrict__ kws, unsigned short* __restrict__ qv,
    float* __restrict__ out)
{
    __shared__ __align__(16) unsigned short xs[32 * 132];
    const int t   = threadIdx.x;
    const int wid = t >> 6;          // 0..15
    const int m   = wid >> 2;        // matrix
    const int ct  = wid & 3;         // col tile
    const int l   = t & 63;
    const int col = ct * 32 + (l & 31);
    const int kb  = (l >> 5) * 8;

    // B fragments, loaded once (L2-resident after first blocks)
    v8bf b[8];
    {
        const unsigned short* wp = Wt + m * 16384 + col * 128 + kb;
        #pragma unroll
        for (int c = 0; c < 8; ++c) b[c] = *(const v8bf*)(wp + c * 16);
    }
    const float* bvec = (m == 0) ? bk : (m == 1) ? bq : (m == 2) ? bv : bs;
    const float bcol = bvec[col] * ((m < 2) ? LOG2E : 1.0f);
    unsigned short* dst; int dstride;
    if (m == 0)      { dst = kws;      dstride = 128; }
    else if (m == 1) { dst = qv;       dstride = 256; }
    else             { dst = qv + 128; dstride = 256; }   // m==2 (v half)

    // staging: thread owns one float4 of the 32x128 tile
    const int srow = t >> 5;         // 0..31
    const int sk4  = (t & 31) << 2;  // 0..124
    const int rowb = 4 * (l >> 5);

    const int ntiles = (N + 31) >> 5;
    int tile = blockIdx.x;
    if (tile >= ntiles) return;

    float4 stg = make_float4(0.f, 0.f, 0.f, 0.f);
    {
        int gr = tile * 32 + srow;
        if (gr < N) stg = *(const float4*)(x + (size_t)gr * 128 + sk4);
    }

    const unsigned short* ap = xs + (l & 31) * 132 + kb;

    while (true) {
        // write staged tile to LDS as bf16
        ushort4 pk;
        pk.x = f2bf(stg.x); pk.y = f2bf(stg.y);
        pk.z = f2bf(stg.z); pk.w = f2bf(stg.w);
        *(ushort4*)(xs + srow * 132 + sk4) = pk;
        __syncthreads();

        // prefetch next tile while computing this one
        int next = tile + gridDim.x;
        if (next < ntiles) {
            int gr = next * 32 + srow;
            stg = (gr < N) ? *(const float4*)(x + (size_t)gr * 128 + sk4)
                           : make_float4(0.f, 0.f, 0.f, 0.f);
        }

        // fused LDS-read + MFMA chain (a-frags transient: low VGPR)
        v16f acc = {};
        #pragma unroll
        for (int c = 0; c < 8; ++c) {
            v4bf a0 = *(const v4bf*)(ap + c * 16);
            v4bf a1 = *(const v4bf*)(ap + c * 16 + 4);
            v8bf a = __builtin_shufflevector(a0, a1, 0, 1, 2, 3, 4, 5, 6, 7);
            acc = __builtin_amdgcn_mfma_f32_32x32x16_bf16(a, b[c], acc, 0, 0, 0);
        }

        // C/D: col = lane&31, row = (reg&3) + 8*(reg>>2) + 4*(lane>>5)
        const int r0 = tile * 32 + rowb;
        if (m == 3) {
            #pragma unroll
            for (int reg = 0; reg < 16; ++reg) {
                int row = r0 + (reg & 3) + 8 * (reg >> 2);
                if (row < N) out[(size_t)row * 128 + col] = acc[reg] + bcol;
            }
        } else {
            #pragma unroll
            for (int reg = 0; reg < 16; ++reg) {
                int row = r0 + (reg & 3) + 8 * (reg >> 2);
                if (row < N) dst[(size_t)row * dstride + col] = f2bf(acc[reg] + bcol);
            }
        }

        tile = next;
        if (tile >= ntiles) break;
        __syncthreads();   // all A-frag reads done before next staging write
    }
}

// ---------------- Phase 2: device-built CSR (counting sort by dst) ----------------

__global__ __launch_bounds__(256) void count_deg(
    const int* __restrict__ ei, int E, int* __restrict__ deg)
{
    int e = blockIdx.x * 256 + threadIdx.x;
    if (e >= E) return;
    atomicAdd(&deg[ei[E + e]], 1);   // dst
}

__global__ __launch_bounds__(256) void scan_chunks(
    const int* __restrict__ deg, int N, int* __restrict__ rowStart,
    int* __restrict__ chunkTot)
{
    __shared__ int sums[256];
    const int t = threadIdx.x;
    const int base = blockIdx.x * 1024 + t * 4;
    int d0 = 0, d1 = 0, d2 = 0, d3 = 0;
    if (base + 3 < N) {
        int4 dd = *(const int4*)(deg + base);
        d0 = dd.x; d1 = dd.y; d2 = dd.z; d3 = dd.w;
    } else {
        if (base + 0 < N) d0 = deg[base + 0];
        if (base + 1 < N) d1 = deg[base + 1];
        if (base + 2 < N) d2 = deg[base + 2];
        if (base + 3 < N) d3 = deg[base + 3];
    }
    int tot = d0 + d1 + d2 + d3;
    sums[t] = tot;
    __syncthreads();
    #pragma unroll
    for (int off = 1; off < 256; off <<= 1) {
        int v = (t >= off) ? sums[t - off] : 0;
        __syncthreads();
        sums[t] += v;
        __syncthreads();
    }
    int excl = sums[t] - tot;
    if (base + 0 < N) rowStart[base + 0] = excl;
    if (base + 1 < N) rowStart[base + 1] = excl + d0;
    if (base + 2 < N) rowStart[base + 2] = excl + d0 + d1;
    if (base + 3 < N) rowStart[base + 3] = excl + d0 + d1 + d2;
    if (t == 255) chunkTot[blockIdx.x] = sums[255];
}

// add chunk offsets; each block re-scans the (<=128) chunk totals in LDS
__global__ __launch_bounds__(256) void add_offsets(
    int* __restrict__ rowStart, int* __restrict__ rowEnd,
    const int* __restrict__ chunkTot, int N, int nChunks)
{
    __shared__ int s[128];
    const int t = threadIdx.x;
    if (t < 128) s[t] = (t < nChunks) ? chunkTot[t] : 0;
    __syncthreads();
    #pragma unroll
    for (int off = 1; off < 128; off <<= 1) {
        int u = 0;
        if (t < 128 && t >= off) u = s[t - off];
        __syncthreads();
        if (t < 128) s[t] += u;
        __syncthreads();
    }
    const int coff = (blockIdx.x == 0) ? 0 : s[blockIdx.x - 1];
    const int base = blockIdx.x * 1024 + t * 4;
    if (base + 3 < N) {
        int4 r = *(const int4*)(rowStart + base);
        r.x += coff; r.y += coff; r.z += coff; r.w += coff;
        *(int4*)(rowStart + base) = r;
        *(int4*)(rowEnd + base) = r;
    } else {
        #pragma unroll
        for (int j = 0; j < 4; ++j) {
            if (base + j < N) {
                int v = rowStart[base + j] + coff;
                rowStart[base + j] = v;
                rowEnd[base + j] = v;
            }
        }
    }
}

__global__ __launch_bounds__(256) void fill_csr(
    const int* __restrict__ ei, int E,
    int* __restrict__ rowEnd, int* __restrict__ elist)
{
    int e = blockIdx.x * 256 + threadIdx.x;
    if (e >= E) return;
    int s = ei[e];
    int d = ei[E + e];
    int pos = atomicAdd(&rowEnd[d], 1);
    elist[pos] = s;
}

// ---------------- Phase 3: owner-computes aggregation (no atomics) ----------------
// 4 nodes/wave (16 lanes each), lane owns 8 feats; q|v interleaved rows.
// Sigmoid in 5 VALU/feature: k',q' pre-scaled by log2e, nk = -k' via packed
// sign-flip, then arg=nk-q'; e=v_exp_f32(arg); eta=v_rcp_f32(1+e); fma.
__global__ __launch_bounds__(256) void gather_agg(
    const int* __restrict__ rowStart, const int* __restrict__ rowEnd,
    const int* __restrict__ elist,
    const unsigned short* __restrict__ kws,
    const unsigned short* __restrict__ qv,
    float* __restrict__ out, int N)
{
    int gid = blockIdx.x * 256 + threadIdx.x;
    int node = gid >> 4;
    if (node >= N) return;
    int fo = (gid & 15) << 3;   // 8 feats per lane

    uint4 kraw = *(const uint4*)(kws + (size_t)node * 128 + fo);
    // packed negate (bf16 sign bits): nk = -k'
    kraw.x ^= 0x80008000u; kraw.y ^= 0x80008000u;
    kraw.z ^= 0x80008000u; kraw.w ^= 0x80008000u;
    float nkf[8];
    unpack8(kraw, nkf);
    float acc[8] = {};

    const unsigned short* qvb = qv + fo;
    int p = rowStart[node];
    const int e = rowEnd[node];

    for (; p + 4 <= e; p += 4) {
        int s0 = elist[p], s1 = elist[p + 1], s2 = elist[p + 2], s3 = elist[p + 3];
        const unsigned short* r0 = qvb + (size_t)s0 * 256;
        const unsigned short* r1 = qvb + (size_t)s1 * 256;
        const unsigned short* r2 = qvb + (size_t)s2 * 256;
        const unsigned short* r3 = qvb + (size_t)s3 * 256;
        uint4 q0r = *(const uint4*)(r0);
        uint4 v0r = *(const uint4*)(r0 + 128);
        uint4 q1r = *(const uint4*)(r1);
        uint4 v1r = *(const uint4*)(r1 + 128);
        uint4 q2r = *(const uint4*)(r2);
        uint4 v2r = *(const uint4*)(r2 + 128);
        uint4 q3r = *(const uint4*)(r3);
        uint4 v3r = *(const uint4*)(r3 + 128);
        float qf[8], vf[8];
        unpack8(q0r, qf); unpack8(v0r, vf);
        #pragma unroll
        for (int j = 0; j < 8; ++j) {
            float ex = __builtin_amdgcn_exp2f(nkf[j] - qf[j]);
            acc[j] = fmaf(__builtin_amdgcn_rcpf(1.0f + ex), vf[j], acc[j]);
        }
        unpack8(q1r, qf); unpack8(v1r, vf);
        #pragma unroll
        for (int j = 0; j < 8; ++j) {
            float ex = __builtin_amdgcn_exp2f(nkf[j] - qf[j]);
            acc[j] = fmaf(__builtin_amdgcn_rcpf(1.0f + ex), vf[j], acc[j]);
        }
        unpack8(q2r, qf); unpack8(v2r, vf);
        #pragma unroll
        for (int j = 0; j < 8; ++j) {
            float ex = __builtin_amdgcn_exp2f(nkf[j] - qf[j]);
            acc[j] = fmaf(__builtin_amdgcn_rcpf(1.0f + ex), vf[j], acc[j]);
        }
        unpack8(q3r, qf); unpack8(v3r, vf);
        #pragma unroll
        for (int j = 0; j < 8; ++j) {
            float ex = __builtin_amdgcn_exp2f(nkf[j] - qf[j]);
            acc[j] = fmaf(__builtin_amdgcn_rcpf(1.0f + ex), vf[j], acc[j]);
        }
    }
    for (; p < e; ++p) {
        int s0 = elist[p];
        const unsigned short* r0 = qvb + (size_t)s0 * 256;
        uint4 q0r = *(const uint4*)(r0);
        uint4 v0r = *(const uint4*)(r0 + 128);
        float qf[8], vf[8];
        unpack8(q0r, qf); unpack8(v0r, vf);
        #pragma unroll
        for (int j = 0; j < 8; ++j) {
            float ex = __builtin_amdgcn_exp2f(nkf[j] - qf[j]);
            acc[j] = fmaf(__builtin_amdgcn_rcpf(1.0f + ex), vf[j], acc[j]);
        }
    }

    float* orow = out + (size_t)node * 128 + fo;
    float4 o0 = *(float4*)(orow);
    float4 o1 = *(float4*)(orow + 4);
    o0.x += acc[0]; o0.y += acc[1]; o0.z += acc[2]; o0.w += acc[3];
    o1.x += acc[4]; o1.y += acc[5]; o1.z += acc[6]; o1.w += acc[7];
    *(float4*)(orow)     = o0;
    *(float4*)(orow + 4) = o1;
}

extern "C" void kernel_launch(void* const* d_in, const int* in_sizes, int n_in,
                              void* d_out, int out_size, void* d_ws, size_t ws_size,
                              hipStream_t stream) {
    const float* x    = (const float*)d_in[0];
    const int*   ei   = (const int*)d_in[1];
    const float* Wk   = (const float*)d_in[3];
    const float* bk   = (const float*)d_in[4];
    const float* Wq   = (const float*)d_in[5];
    const float* bq   = (const float*)d_in[6];
    const float* Wv   = (const float*)d_in[7];
    const float* bv   = (const float*)d_in[8];
    const float* Ws   = (const float*)d_in[9];
    const float* bias = (const float*)d_in[10];

    const int N = in_sizes[0] / 128;
    const int E = in_sizes[1] / 2;
    float* out = (float*)d_out;

    // workspace layout
    unsigned short* kws = (unsigned short*)d_ws;        // N*128 bf16 (k', scaled)
    unsigned short* qv  = kws + (size_t)N * 128;        // N*256 bf16 (q'|v)
    int* deg      = (int*)(qv + (size_t)N * 256);
    int* rowStart = deg + N;
    int* rowEnd   = rowStart + N;
    int* chunkTot = rowEnd + N;
    int* elist    = chunkTot + 128;
    unsigned short* Wt = (unsigned short*)(elist + E);

    const int nChunks = (N + 1023) / 1024;

    prep_w_zero<<<512, 256, 0, stream>>>(Wk, Wq, Wv, Ws, Wt, deg, N);
    gemm_fused<<<1024, 1024, 0, stream>>>(
        x, N, Wt, bk, bq, bv, bias, kws, qv, out);

    count_deg<<<(E + 255) / 256, 256, 0, stream>>>(ei, E, deg);
    scan_chunks<<<nChunks, 256, 0, stream>>>(deg, N, rowStart, chunkTot);
    add_offsets<<<nChunks, 256, 0, stream>>>(rowStart, rowEnd, chunkTot, N, nChunks);
    fill_csr<<<(E + 255) / 256, 256, 0, stream>>>(ei, E, rowEnd, elist);

    gather_agg<<<((size_t)N * 16 + 255) / 256, 256, 0, stream>>>(
        rowStart, rowEnd, elist, kws, qv, out, N);
}